// Round 2
// baseline (1200.777 us; speedup 1.0000x reference)
//
#include <hip/hip_runtime.h>
#include <stdint.h>

typedef unsigned short u16;
typedef unsigned int u32;
typedef __attribute__((ext_vector_type(8))) short short8;   // 8 bf16 (4 VGPR)
typedef __attribute__((ext_vector_type(4))) float f32x4;

#define WAVES 6
#define NTHR 384
#define K2E16 0.09016844005556021f   /* log2(e)/16 : scores/sqrt(256) folded into exp2 */

static __device__ __forceinline__ u16 f2bf(float f) {
  union { float f; u32 u; } v; v.f = f;
  u32 r = v.u + 0x7FFFu + ((v.u >> 16) & 1u);   // RNE
  return (u16)(r >> 16);
}

// ---------------------------------------------------------------------------
// K0: weight prep.
//  - Wvo = Wv @ Wo (f32), stored bf16 in MFMA-B fragment layout (K=256)
//  - WqF/WkF: bf16 fragment layout (K=128)
//  - bvo = bv @ Wo + bo (f32)
// Fragment layout (16x16x32 B operand): for (k,col):
//   idx = ((kt*16 + nt)*64 + g*16 + (col&15))*8 + e, kt=k>>5, g=(k>>3)&3, e=k&7, nt=col>>4
// ---------------------------------------------------------------------------
__global__ __launch_bounds__(256) void k_setup(
    const float* __restrict__ Wq, const float* __restrict__ Wk,
    const float* __restrict__ Wv, const float* __restrict__ Wo,
    const float* __restrict__ bv, const float* __restrict__ bo,
    u16* __restrict__ WqF, u16* __restrict__ WkF, u16* __restrict__ WvoF,
    float* __restrict__ bvo) {
  const int ci = blockIdx.x;   // k-row
  const int co = threadIdx.x;  // col
  float acc = 0.f;
  for (int h = 0; h < 256; ++h)
    acc += Wv[ci*256 + h] * Wo[h*256 + co];
  const int idx = (((ci>>5)*16 + (co>>4))*64 + (((ci>>3)&3)*16 + (co&15)))*8 + (ci&7);
  WvoF[idx] = f2bf(acc);
  if (ci < 128) {
    WqF[idx] = f2bf(Wq[ci*256 + co]);
    WkF[idx] = f2bf(Wk[ci*256 + co]);
  }
  if (ci == 0) {
    float a2 = 0.f;
    for (int h = 0; h < 256; ++h) a2 += bv[h] * Wo[h*256 + co];
    bvo[co] = a2 + bo[co];
  }
}

// ---------------------------------------------------------------------------
// K1: enc2[b,n] = bf16(enc[b,:,n,:]) @ Wvo  (96x256 @ 256x256), written to ws
// in sigma-matched B-fragment layout so K2 can consume it with zero shuffling:
//   frag (ct,kb), lane l, elem e  holds enc2[p][c] with
//   p = 32*kb + 16*(e>>2) + 4*(l>>4) + (e&3),  c = (l&15) + 16*ct
// 6 waves; waves partition the 16 output col-tiles (nt = wave + 6*i).
// ---------------------------------------------------------------------------
__global__ __launch_bounds__(NTHR) void k_enc2(
    const float* __restrict__ enc, const u16* __restrict__ WvoF,
    u16* __restrict__ enc2F, int n0) {
  extern __shared__ char smem[];
  char* encL = smem;  // 96 rows * 512B bf16, XOR-swizzled
  const int n = n0 + blockIdx.x, b = blockIdx.y;
  const int tid = threadIdx.x, wave = tid >> 6, lane = tid & 63;
  const int g = lane >> 4, c15 = lane & 15;

  // stage enc rows: 1KB f32 per row -> 512B bf16, swizzle byte ^= (row&7)<<4
  for (int r = wave; r < 96; r += WAVES) {
    const float4 v = *(const float4*)(enc + ((size_t)((b*96 + r)*1024 + n))*256 + lane*4);
    u32 lo = (u32)f2bf(v.x) | ((u32)f2bf(v.y) << 16);
    u32 hi = (u32)f2bf(v.z) | ((u32)f2bf(v.w) << 16);
    u32* d = (u32*)(encL + r*512 + ((lane*8) ^ ((r & 7) << 4)));
    d[0] = lo; d[1] = hi;
  }
  __syncthreads();

  f32x4 acc[3][6];
  #pragma unroll
  for (int i = 0; i < 3; ++i)
    #pragma unroll
    for (int mt = 0; mt < 6; ++mt) acc[i][mt] = (f32x4)0.f;

  #pragma unroll
  for (int kt = 0; kt < 8; ++kt) {
    short8 a[6];
    #pragma unroll
    for (int mt = 0; mt < 6; ++mt) {
      const int row = 16*mt + c15;
      a[mt] = *(const short8*)(encL + row*512 + ((16*g + 64*kt) ^ ((row & 7) << 4)));
    }
    #pragma unroll
    for (int i = 0; i < 3; ++i) {
      const int nt = wave + 6*i;
      if (nt < 16) {
        const short8 bf = *(const short8*)(WvoF + (size_t)((kt*16 + nt)*64 + lane)*8);
        #pragma unroll
        for (int mt = 0; mt < 6; ++mt)
          acc[i][mt] = __builtin_amdgcn_mfma_f32_16x16x32_bf16(a[mt], bf, acc[i][mt], 0, 0, 0);
      }
    }
  }

  // epilogue: C-layout (row p = 16*mt+4*g+r, col c = c15+16*nt) -> fragment scatter.
  // kb = mt>>1, e = 4*(mt&1)+r, target lane == lane: 4 r's pack into one 8B store.
  u16* dstF = enc2F + (size_t)(blockIdx.y * (u32)gridDim.x + blockIdx.x) * 24576;
  #pragma unroll
  for (int i = 0; i < 3; ++i) {
    const int nt = wave + 6*i;
    if (nt < 16) {
      #pragma unroll
      for (int mt = 0; mt < 6; ++mt) {
        uint2 o;
        o.x = (u32)f2bf(acc[i][mt][0]) | ((u32)f2bf(acc[i][mt][1]) << 16);
        o.y = (u32)f2bf(acc[i][mt][2]) | ((u32)f2bf(acc[i][mt][3]) << 16);
        *(uint2*)(dstF + ((nt*3 + (mt >> 1))*64 + lane)*8 + (mt & 1)*4) = o;
      }
    }
  }
}

// ---------------------------------------------------------------------------
// K2: per (b,n): q = ste_dec@Wq+bq, k = ste_enc@Wk+bk (bf16 MFMA, into LDS),
// scoresT = mfma(K,Q) (lane-local softmax column), softmax (deferred 1/sum),
// out = attn @ enc2 (attn straight from regs via sigma packing), epilogue
// applies 1/sum and +bvo, stores f32.
// LDS: qL 48K | kL 48K | xL 48K (sd+se, later enc2) | biases 3K  = 150528B
// ---------------------------------------------------------------------------
__global__ __launch_bounds__(NTHR) void k_attn(
    const float* __restrict__ sdec, const float* __restrict__ senc,
    const float* __restrict__ bq, const float* __restrict__ bk,
    const u16* __restrict__ WqF, const u16* __restrict__ WkF,
    const u16* __restrict__ enc2F, const float* __restrict__ bvo,
    float* __restrict__ out, int n0) {
  extern __shared__ char smem[];
  char* qL = smem;                       // 49152
  char* kL = smem + 49152;               // 49152
  char* xL = smem + 98304;               // 49152: sd(24576)+se(24576), later enc2
  float* bqL  = (float*)(smem + 147456);
  float* bkL  = (float*)(smem + 148480);
  float* bvoL = (float*)(smem + 149504);

  const int n = n0 + blockIdx.x, b = blockIdx.y;
  const int tid = threadIdx.x, wave = tid >> 6, lane = tid & 63;
  const int g = lane >> 4, c15 = lane & 15;

  char* sdL = xL;
  char* seL = xL + 24576;

  // stage ste_dec / ste_enc rows (512B f32 -> 256B bf16, swizzled)
  for (int i = wave; i < 48; i += WAVES) {
    const int r = 2*i + (lane >> 5);
    const int cl = lane & 31;
    {
      const float4 v = *(const float4*)(sdec + ((size_t)((b*96 + r)*1024 + n))*128 + cl*4);
      u32 lo = (u32)f2bf(v.x) | ((u32)f2bf(v.y) << 16);
      u32 hi = (u32)f2bf(v.z) | ((u32)f2bf(v.w) << 16);
      u32* d = (u32*)(sdL + r*256 + ((cl*8) ^ ((r & 7) << 4)));
      d[0] = lo; d[1] = hi;
    }
    {
      const float4 v = *(const float4*)(senc + ((size_t)((b*96 + r)*1024 + n))*128 + cl*4);
      u32 lo = (u32)f2bf(v.x) | ((u32)f2bf(v.y) << 16);
      u32 hi = (u32)f2bf(v.z) | ((u32)f2bf(v.w) << 16);
      u32* d = (u32*)(seL + r*256 + ((cl*8) ^ ((r & 7) << 4)));
      d[0] = lo; d[1] = hi;
    }
  }
  if (tid < 256) { bqL[tid] = bq[tid]; bkL[tid] = bk[tid]; bvoL[tid] = bvo[tid]; }
  __syncthreads();

  // ---- q projection (M=96 rows, K=128, N=256; waves partition N) ----
  {
    f32x4 acc[3][6];
    #pragma unroll
    for (int i = 0; i < 3; ++i)
      #pragma unroll
      for (int mt = 0; mt < 6; ++mt) acc[i][mt] = (f32x4)0.f;
    #pragma unroll
    for (int kt = 0; kt < 4; ++kt) {
      short8 a[6];
      #pragma unroll
      for (int mt = 0; mt < 6; ++mt) {
        const int row = 16*mt + c15;
        a[mt] = *(const short8*)(sdL + row*256 + ((16*g + 64*kt) ^ ((row & 7) << 4)));
      }
      #pragma unroll
      for (int i = 0; i < 3; ++i) {
        const int nt = wave + 6*i;
        if (nt < 16) {
          const short8 bf = *(const short8*)(WqF + (size_t)((kt*16 + nt)*64 + lane)*8);
          #pragma unroll
          for (int mt = 0; mt < 6; ++mt)
            acc[i][mt] = __builtin_amdgcn_mfma_f32_16x16x32_bf16(a[mt], bf, acc[i][mt], 0, 0, 0);
        }
      }
    }
    #pragma unroll
    for (int i = 0; i < 3; ++i) {
      const int nt = wave + 6*i;
      if (nt < 16) {
        const float bqv = bqL[c15 + 16*nt];
        #pragma unroll
        for (int mt = 0; mt < 6; ++mt) {
          #pragma unroll
          for (int r = 0; r < 4; ++r) {
            const int row = 16*mt + 4*g + r;
            *(u16*)(qL + row*512 + ((2*c15 + 32*nt) ^ ((row & 7) << 4))) =
                f2bf(acc[i][mt][r] + bqv);
          }
        }
      }
    }
  }
  // ---- k projection ----
  {
    f32x4 acc[3][6];
    #pragma unroll
    for (int i = 0; i < 3; ++i)
      #pragma unroll
      for (int mt = 0; mt < 6; ++mt) acc[i][mt] = (f32x4)0.f;
    #pragma unroll
    for (int kt = 0; kt < 4; ++kt) {
      short8 a[6];
      #pragma unroll
      for (int mt = 0; mt < 6; ++mt) {
        const int row = 16*mt + c15;
        a[mt] = *(const short8*)(seL + row*256 + ((16*g + 64*kt) ^ ((row & 7) << 4)));
      }
      #pragma unroll
      for (int i = 0; i < 3; ++i) {
        const int nt = wave + 6*i;
        if (nt < 16) {
          const short8 bf = *(const short8*)(WkF + (size_t)((kt*16 + nt)*64 + lane)*8);
          #pragma unroll
          for (int mt = 0; mt < 6; ++mt)
            acc[i][mt] = __builtin_amdgcn_mfma_f32_16x16x32_bf16(a[mt], bf, acc[i][mt], 0, 0, 0);
        }
      }
    }
    #pragma unroll
    for (int i = 0; i < 3; ++i) {
      const int nt = wave + 6*i;
      if (nt < 16) {
        const float bkv = bkL[c15 + 16*nt];
        #pragma unroll
        for (int mt = 0; mt < 6; ++mt) {
          #pragma unroll
          for (int r = 0; r < 4; ++r) {
            const int row = 16*mt + 4*g + r;
            *(u16*)(kL + row*512 + ((2*c15 + 32*nt) ^ ((row & 7) << 4))) =
                f2bf(acc[i][mt][r] + bkv);
          }
        }
      }
    }
  }
  __syncthreads();   // q,k visible; sd/se dead -> xL reusable for enc2

  // prefetch enc2 fragments (48KB) to regs; LDS-write deferred past scoresT
  const f32x4* esrc = (const f32x4*)(enc2F + (size_t)(blockIdx.y * (u32)gridDim.x + blockIdx.x) * 24576);
  f32x4 pre[8];
  #pragma unroll
  for (int i = 0; i < 8; ++i) pre[i] = esrc[tid + 384*i];

  // ---- scoresT = K @ Q^T for this wave's 16 query columns ----
  f32x4 sac[6];
  #pragma unroll
  for (int pt = 0; pt < 6; ++pt) sac[pt] = (f32x4)0.f;
  const int qrow = 16*wave + c15;
  const int qx = (qrow & 7) << 4;
  #pragma unroll
  for (int kt = 0; kt < 8; ++kt) {
    const short8 qf = *(const short8*)(qL + qrow*512 + ((16*g + 64*kt) ^ qx));
    #pragma unroll
    for (int pt = 0; pt < 6; ++pt) {
      const int row = 16*pt + c15;
      const short8 kf = *(const short8*)(kL + row*512 + ((16*g + 64*kt) ^ ((row & 7) << 4)));
      sac[pt] = __builtin_amdgcn_mfma_f32_16x16x32_bf16(kf, qf, sac[pt], 0, 0, 0);
    }
  }

  // ---- softmax over p (rows); column qi = 16*wave + c15 lives in lanes {l, l^16, l^32} ----
  float m = sac[0][0];
  #pragma unroll
  for (int pt = 0; pt < 6; ++pt)
    #pragma unroll
    for (int r = 0; r < 4; ++r) m = fmaxf(m, sac[pt][r]);
  m = fmaxf(m, __shfl_xor(m, 16));
  m = fmaxf(m, __shfl_xor(m, 32));
  float s = 0.f;
  #pragma unroll
  for (int pt = 0; pt < 6; ++pt)
    #pragma unroll
    for (int r = 0; r < 4; ++r) {
      const float e = exp2f((sac[pt][r] - m) * K2E16);
      sac[pt][r] = e; s += e;
    }
  s += __shfl_xor(s, 16);
  s += __shfl_xor(s, 32);
  const float rs = 1.f / s;

  // ---- attn A-fragments straight from regs (sigma packing; pure in-lane) ----
  short8 af[3];
  #pragma unroll
  for (int kb = 0; kb < 3; ++kb) {
    union { u32 u[4]; short8 v; } cv;
    cv.u[0] = (u32)f2bf(sac[2*kb][0])   | ((u32)f2bf(sac[2*kb][1])   << 16);
    cv.u[1] = (u32)f2bf(sac[2*kb][2])   | ((u32)f2bf(sac[2*kb][3])   << 16);
    cv.u[2] = (u32)f2bf(sac[2*kb+1][0]) | ((u32)f2bf(sac[2*kb+1][1]) << 16);
    cv.u[3] = (u32)f2bf(sac[2*kb+1][2]) | ((u32)f2bf(sac[2*kb+1][3]) << 16);
    af[kb] = cv.v;
  }

  // commit enc2 to LDS, sync
  f32x4* e2w = (f32x4*)xL;
  #pragma unroll
  for (int i = 0; i < 8; ++i) e2w[tid + 384*i] = pre[i];
  __syncthreads();

  float rsr[4];
  #pragma unroll
  for (int r = 0; r < 4; ++r) rsr[r] = __shfl(rs, 4*g + r);

  // ---- out = attn @ enc2; epilogue: *1/sum + bvo; f32 store ----
  #pragma unroll
  for (int nt = 0; nt < 16; ++nt) {
    f32x4 oa = (f32x4)0.f;
    #pragma unroll
    for (int kb = 0; kb < 3; ++kb) {
      const short8 ef = *(const short8*)(xL + (((nt*3 + kb)*64 + lane) << 4));
      oa = __builtin_amdgcn_mfma_f32_16x16x32_bf16(af[kb], ef, oa, 0, 0, 0);
    }
    const int c = c15 + 16*nt;
    const float bz = bvoL[c];
    #pragma unroll
    for (int r = 0; r < 4; ++r) {
      const int qi = 16*wave + 4*g + r;
      out[((size_t)((b*96 + qi)*1024 + n))*256 + c] = oa[r]*rsr[r] + bz;
    }
  }
}

// ---------------------------------------------------------------------------
extern "C" void kernel_launch(void* const* d_in, const int* in_sizes, int n_in,
                              void* d_out, int out_size, void* d_ws, size_t ws_size,
                              hipStream_t stream) {
  const float* enc     = (const float*)d_in[0];
  const float* ste_enc = (const float*)d_in[1];
  const float* ste_dec = (const float*)d_in[2];
  const float* Wq = (const float*)d_in[3];
  const float* bq = (const float*)d_in[4];
  const float* Wk = (const float*)d_in[5];
  const float* bk = (const float*)d_in[6];
  const float* Wv = (const float*)d_in[7];
  const float* bv = (const float*)d_in[8];
  const float* Wo = (const float*)d_in[9];
  const float* bo = (const float*)d_in[10];
  float* out = (float*)d_out;

  u16*   WqF   = (u16*)d_ws;                              // 65536 B
  u16*   WkF   = (u16*)((char*)d_ws + 65536);             // 65536 B
  u16*   WvoF  = (u16*)((char*)d_ws + 131072);            // 131072 B
  float* bvo   = (float*)((char*)d_ws + 262144);          // 1024 B
  u16*   enc2F = (u16*)((char*)d_ws + 263168);            // chunk*8*49152 B

  (void)hipFuncSetAttribute((const void*)k_attn,
        hipFuncAttributeMaxDynamicSharedMemorySize, 150528);
  (void)hipFuncSetAttribute((const void*)k_enc2,
        hipFuncAttributeMaxDynamicSharedMemorySize, 49152);

  int chunk = 128;
  while (chunk > 1 && (263168ull + (size_t)chunk * 8ull * 49152ull) > ws_size)
    chunk >>= 1;

  k_setup<<<dim3(256), dim3(256), 0, stream>>>(Wq, Wk, Wv, Wo, bv, bo,
                                               WqF, WkF, WvoF, bvo);
  for (int n0 = 0; n0 < 1024; n0 += chunk) {
    k_enc2<<<dim3(chunk, 8), dim3(NTHR), 49152, stream>>>(enc, WvoF, enc2F, n0);
    k_attn<<<dim3(chunk, 8), dim3(NTHR), 150528, stream>>>(ste_dec, ste_enc, bq, bk,
                                                           WqF, WkF, enc2F, bvo, out, n0);
  }
}